// Round 1
// baseline (2057.839 us; speedup 1.0000x reference)
//
#include <hip/hip_runtime.h>
#include <hip/hip_bf16.h>

typedef __bf16 bf16_t;
typedef __bf16 bf16x2 __attribute__((ext_vector_type(2)));
typedef __bf16 bf16x4 __attribute__((ext_vector_type(4)));
typedef __bf16 bf16x8 __attribute__((ext_vector_type(8)));
typedef float f32x4 __attribute__((ext_vector_type(4)));

#define DIM     1024
#define NEXP    8
#define VOCAB   16384
#define HIDDEN  2730
#define UPOUT   5460
#define NTOK    2048
#define NSLOT   4096
#define HRAW_LD 5472
#define H1_LD   2752
#define MAXTILES 39

// ---------------- router: scores, top-2, softmax weights, histogram ----------------
__global__ __launch_bounds__(256) void router_kernel(const float* __restrict__ x,
        const float* __restrict__ wr, int* __restrict__ slot_ids,
        float* __restrict__ slot_w, int* __restrict__ counts) {
    const int lane = threadIdx.x & 63;
    const int wave = threadIdx.x >> 6;
    const int token = blockIdx.x * 4 + wave;
    const float* xrow = x + (size_t)token * DIM;
    float acc[NEXP];
#pragma unroll
    for (int e = 0; e < NEXP; ++e) acc[e] = 0.f;
#pragma unroll
    for (int i = 0; i < DIM / 64; ++i) {
        const int k = i * 64 + lane;
        const float xv = xrow[k];
#pragma unroll
        for (int e = 0; e < NEXP; ++e) acc[e] += xv * wr[e * DIM + k];
    }
#pragma unroll
    for (int off = 32; off > 0; off >>= 1) {
#pragma unroll
        for (int e = 0; e < NEXP; ++e) acc[e] += __shfl_xor(acc[e], off);
    }
    if (lane == 0) {
        float c0 = -1e30f; int b0 = 0;
#pragma unroll
        for (int e = 0; e < NEXP; ++e) if (acc[e] > c0) { c0 = acc[e]; b0 = e; }
        float c1 = -1e30f; int b1 = 0;
#pragma unroll
        for (int e = 0; e < NEXP; ++e) if (e != b0 && acc[e] > c1) { c1 = acc[e]; b1 = e; }
        slot_ids[token * 2 + 0] = b0;
        slot_ids[token * 2 + 1] = b1;
        const float w0 = 1.f / (1.f + expf(c1 - c0));
        slot_w[token * 2 + 0] = w0;
        slot_w[token * 2 + 1] = 1.f - w0;
        atomicAdd(&counts[b0], 1);
        atomicAdd(&counts[b1], 1);
    }
}

// ---------------- scheduler: offsets, tile list, stable counting-sort ranks ----------------
__global__ __launch_bounds__(512) void sched_kernel(const int* __restrict__ counts,
        int* __restrict__ ntiles, int* __restrict__ tile_e, int* __restrict__ tile_m0,
        int* __restrict__ tile_mend, const int* __restrict__ slot_ids,
        int* __restrict__ slot_of_pos) {
    __shared__ int offs[NEXP];
    if (threadIdx.x == 0) {
        int o = 0, nt = 0;
        for (int e = 0; e < NEXP; ++e) {
            offs[e] = o;
            const int c = counts[e];
            for (int m = 0; m < c; m += 128) {
                tile_e[nt] = e; tile_m0[nt] = o + m; tile_mend[nt] = o + c; ++nt;
            }
            o += c;
        }
        *ntiles = nt;
    }
    __syncthreads();
    const int e = threadIdx.x >> 6;
    const int lane = threadIdx.x & 63;
    int base = offs[e];
    for (int ch = 0; ch < NSLOT / 64; ++ch) {
        const int i = ch * 64 + lane;
        const int id = slot_ids[i];
        const unsigned long long m = __ballot(id == e);
        if (id == e) {
            const int rank = __popcll(m & ((1ull << lane) - 1ull));
            slot_of_pos[base + rank] = i;
        }
        base += __popcll(m);
    }
}

// ---------------- gather tokens into sorted order, fp32 -> bf16 ----------------
__global__ __launch_bounds__(256) void gather_kernel(const float* __restrict__ x,
        const int* __restrict__ slot_of_pos, bf16_t* __restrict__ xs) {
    const int row = blockIdx.x;
    const int t = threadIdx.x;
    const int tok = slot_of_pos[row] >> 1;
    const float4 v = *(const float4*)(x + (size_t)tok * DIM + t * 4);
    bf16x4 o;
    o.x = (bf16_t)v.x; o.y = (bf16_t)v.y; o.z = (bf16_t)v.z; o.w = (bf16_t)v.w;
    *(bf16x4*)(xs + (size_t)row * DIM + t * 4) = o;
}

// ---------------- swiglu: h1 = lin * silu(gate), zero-pad K tail ----------------
__global__ __launch_bounds__(256) void swiglu_kernel(const bf16_t* __restrict__ hraw,
        bf16_t* __restrict__ h1) {
    const int row = blockIdx.x;
    const int col = blockIdx.y * 256 + threadIdx.x;
    if (col >= H1_LD) return;
    float o = 0.f;
    if (col < HIDDEN) {
        const float a = (float)hraw[(size_t)row * HRAW_LD + col];
        const float g = (float)hraw[(size_t)row * HRAW_LD + col + HIDDEN];
        o = a * (g / (1.f + expf(-g)));
    }
    h1[(size_t)row * H1_LD + col] = (bf16_t)o;
}

// ---------------- grouped GEMM: C[m,n] = sum_k A[m,k] * W[n,k]  (W fp32, cvt on the fly)
// EPI 0: store bf16   EPI 1: +skip, store bf16   EPI 2: scaled atomicAdd into out
template <int EPI>
__global__ __launch_bounds__(256) void gemm_kernel(
        const bf16_t* __restrict__ A, int lda,
        const float* __restrict__ B, int N, int K,
        bf16_t* __restrict__ C, int ldc,
        const bf16_t* __restrict__ skip,
        const int* __restrict__ slot_of_pos,
        const float* __restrict__ slot_w,
        float* __restrict__ outp,
        const int* __restrict__ tile_e,
        const int* __restrict__ tile_m0,
        const int* __restrict__ tile_mend,
        const int* __restrict__ ntiles) {
    if (blockIdx.y >= (unsigned)*ntiles) return;
    const int e = tile_e[blockIdx.y];
    const int m0 = tile_m0[blockIdx.y];
    const int mend = tile_mend[blockIdx.y];
    const int n0 = blockIdx.x * 128;
    const float* __restrict__ Bexp = B + (size_t)e * N * K;

    __shared__ bf16_t sA[128][32];
    __shared__ bf16_t sB[128][32];

    const int tid = threadIdx.x;
    const int lane = tid & 63;
    const int wave = tid >> 6;
    const int wr = wave >> 1;
    const int wc = wave & 1;
    const int fr = lane & 15;
    const int fq = lane >> 4;

    f32x4 acc[4][4] = {};

    const int KT = (K + 31) >> 5;
    for (int kt = 0; kt < KT; ++kt) {
        const int k0 = kt * 32;
        // stage A tile (bf16): 2 x 16B per thread, row-major [128][32]
#pragma unroll
        for (int i = 0; i < 2; ++i) {
            const int rit = i * 64 + (tid >> 2);
            const int c8 = (tid & 3) * 8;
            int gr = m0 + rit;
            if (gr > NSLOT - 1) gr = NSLOT - 1;  // clamp: garbage rows never stored
            *(uint4*)&sA[rit][c8] = *(const uint4*)(A + (size_t)gr * lda + k0 + c8);
        }
        // stage B tile (fp32 weights -> bf16): 8 x float2 per thread
#pragma unroll
        for (int i = 0; i < 8; ++i) {
            const int rit = i * 16 + (tid >> 4);
            const int c2 = (tid & 15) * 2;
            const int gn = n0 + rit;
            const int k = k0 + c2;
            float2 v = make_float2(0.f, 0.f);
            if (gn < N && k < K)   // K even, c2 even -> pair never straddles K
                v = *(const float2*)(Bexp + (size_t)gn * K + k);
            bf16x2 p;
            p.x = (bf16_t)v.x;
            p.y = (bf16_t)v.y;
            *(bf16x2*)&sB[rit][c2] = p;
        }
        __syncthreads();
        bf16x8 af[4], bfr[4];
#pragma unroll
        for (int mi = 0; mi < 4; ++mi)
            af[mi] = *(const bf16x8*)&sA[wr * 64 + mi * 16 + fr][fq * 8];
#pragma unroll
        for (int ni = 0; ni < 4; ++ni)
            bfr[ni] = *(const bf16x8*)&sB[wc * 64 + ni * 16 + fr][fq * 8];
#pragma unroll
        for (int mi = 0; mi < 4; ++mi)
#pragma unroll
            for (int ni = 0; ni < 4; ++ni)
                acc[mi][ni] = __builtin_amdgcn_mfma_f32_16x16x32_bf16(
                        af[mi], bfr[ni], acc[mi][ni], 0, 0, 0);
        __syncthreads();
    }

    // epilogue: C/D layout col = lane&15, row = (lane>>4)*4 + reg  [m89-verified]
#pragma unroll
    for (int mi = 0; mi < 4; ++mi) {
#pragma unroll
        for (int reg = 0; reg < 4; ++reg) {
            const int r = m0 + wr * 64 + mi * 16 + fq * 4 + reg;
            if (r >= mend) continue;
            int tok = 0; float wgt = 0.f;
            if constexpr (EPI == 2) {
                const int slot = slot_of_pos[r];
                tok = slot >> 1;
                wgt = slot_w[slot];
            }
#pragma unroll
            for (int ni = 0; ni < 4; ++ni) {
                const int c = n0 + wc * 64 + ni * 16 + fr;
                if (c >= N) continue;
                float v = acc[mi][ni][reg];
                if constexpr (EPI == 0) {
                    C[(size_t)r * ldc + c] = (bf16_t)v;
                } else if constexpr (EPI == 1) {
                    v += (float)skip[(size_t)r * DIM + c];
                    C[(size_t)r * ldc + c] = (bf16_t)v;
                } else {
                    unsafeAtomicAdd(&outp[(size_t)tok * VOCAB + c], v * wgt);
                }
            }
        }
    }
}

extern "C" void kernel_launch(void* const* d_in, const int* in_sizes, int n_in,
                              void* d_out, int out_size, void* d_ws, size_t ws_size,
                              hipStream_t stream) {
    const float* x        = (const float*)d_in[0];
    const float* w_router = (const float*)d_in[1];
    const float* w_up     = (const float*)d_in[2];
    const float* w_down   = (const float*)d_in[3];
    const float* w_proj   = (const float*)d_in[4];
    float* out = (float*)d_out;
    char* ws = (char*)d_ws;

    int*    counts      = (int*)(ws + 0);
    int*    ntiles      = (int*)(ws + 64);
    int*    tile_e      = (int*)(ws + 128);
    int*    tile_m0     = (int*)(ws + 320);
    int*    tile_mend   = (int*)(ws + 512);
    int*    slot_ids    = (int*)(ws + 1024);
    float*  slot_w      = (float*)(ws + 20480);
    int*    slot_of_pos = (int*)(ws + 36864);
    bf16_t* x_sorted    = (bf16_t*)(ws + 65536);     //  8 MB  [4096][1024]
    bf16_t* h2          = (bf16_t*)(ws + 8454144);   //  8 MB  [4096][1024]
    bf16_t* h1          = (bf16_t*)(ws + 16842752);  // 22 MB  [4096][2752]
    bf16_t* h_raw       = (bf16_t*)(ws + 39387136);  // 45 MB  [4096][5472]

    hipMemsetAsync(d_out, 0, (size_t)out_size * sizeof(float), stream);
    hipMemsetAsync(d_ws, 0, 1024, stream);

    router_kernel<<<NTOK / 4, 256, 0, stream>>>(x, w_router, slot_ids, slot_w, counts);
    sched_kernel<<<1, 512, 0, stream>>>(counts, ntiles, tile_e, tile_m0, tile_mend,
                                        slot_ids, slot_of_pos);
    gather_kernel<<<NSLOT, 256, 0, stream>>>(x, slot_of_pos, x_sorted);

    gemm_kernel<0><<<dim3((UPOUT + 127) / 128, MAXTILES), 256, 0, stream>>>(
        x_sorted, DIM, w_up, UPOUT, DIM, h_raw, HRAW_LD,
        nullptr, nullptr, nullptr, nullptr, tile_e, tile_m0, tile_mend, ntiles);

    swiglu_kernel<<<dim3(NSLOT, (H1_LD + 255) / 256), 256, 0, stream>>>(h_raw, h1);

    gemm_kernel<1><<<dim3(DIM / 128, MAXTILES), 256, 0, stream>>>(
        h1, H1_LD, w_down, DIM, HIDDEN, h2, DIM,
        x_sorted, nullptr, nullptr, nullptr, tile_e, tile_m0, tile_mend, ntiles);

    gemm_kernel<2><<<dim3(VOCAB / 128, MAXTILES), 256, 0, stream>>>(
        h2, DIM, w_proj, VOCAB, DIM, nullptr, 0,
        nullptr, slot_of_pos, slot_w, out, tile_e, tile_m0, tile_mend, ntiles);
}

// Round 2
// 1086.495 us; speedup vs baseline: 1.8940x; 1.8940x over previous
//
#include <hip/hip_runtime.h>
#include <hip/hip_bf16.h>

typedef __bf16 bf16_t;
typedef __bf16 bf16x2 __attribute__((ext_vector_type(2)));
typedef __bf16 bf16x4 __attribute__((ext_vector_type(4)));
typedef __bf16 bf16x8 __attribute__((ext_vector_type(8)));
typedef float f32x4 __attribute__((ext_vector_type(4)));

#define DIM     1024
#define NEXP    8
#define VOCAB   16384
#define HIDDEN  2730
#define UPOUT   5460
#define NTOK    2048
#define NSLOT   4096
#define HRAW_LD 5472
#define H1_LD   2752
#define MAXTILES 39

__device__ __forceinline__ void gload_lds16(const void* g, void* l) {
    __builtin_amdgcn_global_load_lds((const __attribute__((address_space(1))) void*)g,
                                     (__attribute__((address_space(3))) void*)l, 16, 0, 0);
}
__device__ __forceinline__ void gload_lds4(const void* g, void* l) {
    __builtin_amdgcn_global_load_lds((const __attribute__((address_space(1))) void*)g,
                                     (__attribute__((address_space(3))) void*)l, 4, 0, 0);
}

// ---------------- router: scores, top-2, softmax weights, histogram ----------------
__global__ __launch_bounds__(256) void router_kernel(const float* __restrict__ x,
        const float* __restrict__ wr, int* __restrict__ slot_ids,
        float* __restrict__ slot_w, int* __restrict__ counts) {
    const int lane = threadIdx.x & 63;
    const int wave = threadIdx.x >> 6;
    const int token = blockIdx.x * 4 + wave;
    const float* xrow = x + (size_t)token * DIM;
    float acc[NEXP];
#pragma unroll
    for (int e = 0; e < NEXP; ++e) acc[e] = 0.f;
#pragma unroll
    for (int i = 0; i < DIM / 64; ++i) {
        const int k = i * 64 + lane;
        const float xv = xrow[k];
#pragma unroll
        for (int e = 0; e < NEXP; ++e) acc[e] += xv * wr[e * DIM + k];
    }
#pragma unroll
    for (int off = 32; off > 0; off >>= 1) {
#pragma unroll
        for (int e = 0; e < NEXP; ++e) acc[e] += __shfl_xor(acc[e], off);
    }
    if (lane == 0) {
        float c0 = -1e30f; int b0 = 0;
#pragma unroll
        for (int e = 0; e < NEXP; ++e) if (acc[e] > c0) { c0 = acc[e]; b0 = e; }
        float c1 = -1e30f; int b1 = 0;
#pragma unroll
        for (int e = 0; e < NEXP; ++e) if (e != b0 && acc[e] > c1) { c1 = acc[e]; b1 = e; }
        slot_ids[token * 2 + 0] = b0;
        slot_ids[token * 2 + 1] = b1;
        const float w0 = 1.f / (1.f + expf(c1 - c0));
        slot_w[token * 2 + 0] = w0;
        slot_w[token * 2 + 1] = 1.f - w0;
        atomicAdd(&counts[b0], 1);
        atomicAdd(&counts[b1], 1);
    }
}

// ---------------- scheduler: offsets, tile list, stable counting-sort ranks ----------------
__global__ __launch_bounds__(512) void sched_kernel(const int* __restrict__ counts,
        int* __restrict__ ntiles, int* __restrict__ tile_e, int* __restrict__ tile_m0,
        int* __restrict__ tile_mend, const int* __restrict__ slot_ids,
        int* __restrict__ slot_of_pos) {
    __shared__ int offs[NEXP];
    if (threadIdx.x == 0) {
        int o = 0, nt = 0;
        for (int e = 0; e < NEXP; ++e) {
            offs[e] = o;
            const int c = counts[e];
            for (int m = 0; m < c; m += 128) {
                tile_e[nt] = e; tile_m0[nt] = o + m; tile_mend[nt] = o + c; ++nt;
            }
            o += c;
        }
        *ntiles = nt;
    }
    __syncthreads();
    const int e = threadIdx.x >> 6;
    const int lane = threadIdx.x & 63;
    int base = offs[e];
    for (int ch = 0; ch < NSLOT / 64; ++ch) {
        const int i = ch * 64 + lane;
        const int id = slot_ids[i];
        const unsigned long long m = __ballot(id == e);
        if (id == e) {
            const int rank = __popcll(m & ((1ull << lane) - 1ull));
            slot_of_pos[base + rank] = i;
        }
        base += __popcll(m);
    }
}

// ---------------- gather tokens into sorted order, fp32 -> bf16 ----------------
__global__ __launch_bounds__(256) void gather_kernel(const float* __restrict__ x,
        const int* __restrict__ slot_of_pos, bf16_t* __restrict__ xs) {
    const int row = blockIdx.x;
    const int t = threadIdx.x;
    const int tok = slot_of_pos[row] >> 1;
    const float4 v = *(const float4*)(x + (size_t)tok * DIM + t * 4);
    bf16x4 o;
    o.x = (bf16_t)v.x; o.y = (bf16_t)v.y; o.z = (bf16_t)v.z; o.w = (bf16_t)v.w;
    *(bf16x4*)(xs + (size_t)row * DIM + t * 4) = o;
}

// ---------------- swiglu: h1 = lin * silu(gate), zero-pad K tail ----------------
__global__ __launch_bounds__(256) void swiglu_kernel(const bf16_t* __restrict__ hraw,
        bf16_t* __restrict__ h1) {
    const int row = blockIdx.x;
    const int col = blockIdx.y * 256 + threadIdx.x;
    if (col >= H1_LD) return;
    float o = 0.f;
    if (col < HIDDEN) {
        const float a = (float)hraw[(size_t)row * HRAW_LD + col];
        const float g = (float)hraw[(size_t)row * HRAW_LD + col + HIDDEN];
        o = a * (g / (1.f + expf(-g)));
    }
    h1[(size_t)row * H1_LD + col] = (bf16_t)o;
}

// ---------------- grouped GEMM: C[m,n] = sum_k A[m,k] * W[n,k]
// A bf16 staged to LDS via global_load_lds(16B); W fp32 staged to LDS via
// global_load_lds (16B if rows 16B-aligned, else 4B), cvt fp32->bf16 after ds_read.
// LDS layouts XOR-swizzled via pre-swizzled global source (linear dest).
// EPI 0: store bf16   EPI 1: +skip, store bf16   EPI 2: scaled atomicAdd into out
template <int EPI, bool BW16>
__global__ __launch_bounds__(256) void gemm_kernel(
        const bf16_t* __restrict__ A, int lda,
        const float* __restrict__ B, int N, int K, int KT, long bLast,
        bf16_t* __restrict__ C, int ldc,
        const bf16_t* __restrict__ skip,
        const int* __restrict__ slot_of_pos,
        const float* __restrict__ slot_w,
        float* __restrict__ outp,
        const int* __restrict__ tile_e,
        const int* __restrict__ tile_m0,
        const int* __restrict__ tile_mend,
        const int* __restrict__ ntiles) {
    if (blockIdx.y >= (unsigned)*ntiles) return;
    const int e = tile_e[blockIdx.y];
    const int m0 = tile_m0[blockIdx.y];
    const int mend = tile_mend[blockIdx.y];
    const int n0 = blockIdx.x * 128;
    const float* __restrict__ Bexp = B + (size_t)e * N * K;

    __shared__ bf16_t sA[2][128][32];   // 8 KB x2, 64B rows, col16 ^= (row&3)
    __shared__ float  sB[2][128][32];   // 16 KB x2, 128B rows, col16 ^= (row&7)

    const int tid = threadIdx.x;
    const int lane = tid & 63;
    const int wave = tid >> 6;
    const int wr = wave >> 1;
    const int wc = wave & 1;
    const int fr = lane & 15;
    const int fq = lane >> 4;

    f32x4 acc[4][4] = {};

    auto stage = [&](int buf, int kt) {
        const int k0 = kt * 32;
        // A tile: 8 KB = 8 x 1KB wave-issues (2 per wave). lane -> row rb+(l>>2), unit l&3
#pragma unroll
        for (int j = 0; j < 2; ++j) {
            const int rb = (wave * 2 + j) * 16;
            const int r = rb + (lane >> 2);
            const int gr = min(m0 + r, NSLOT - 1);
            const int c16 = (lane & 3) ^ (r & 3);          // pre-swizzled source unit
            gload_lds16(A + (size_t)gr * lda + k0 + c16 * 8, &sA[buf][rb][0]);
        }
        if constexpr (BW16) {
            // B tile: 16 KB = 16 x 1KB wave-issues (4 per wave). row rb+(l>>3), unit l&7
#pragma unroll
            for (int j = 0; j < 4; ++j) {
                const int rb = (wave * 4 + j) * 8;
                const int r = rb + (lane >> 3);
                const int gr = min(n0 + r, N - 1);
                const int c16 = (lane & 7) ^ (r & 7);
                gload_lds16(Bexp + (size_t)gr * K + k0 + c16 * 4, &sB[buf][rb][0]);
            }
        } else {
            // rows not 16B-aligned (K=2730): 4B lanes, 64 x 256B issues (16 per wave)
#pragma unroll
            for (int j = 0; j < 16; ++j) {
                const int rb = (wave * 16 + j) * 2;
                const int r = rb + (lane >> 5);
                const int gr = min(n0 + r, N - 1);
                const int c16 = ((lane >> 2) & 7) ^ (r & 7);
                long flat = (long)e * N * K + (long)gr * K + k0 + c16 * 4 + (lane & 3);
                if (flat > bLast) flat = bLast;   // K-tail: A is zero there, value irrelevant
                gload_lds4(B + flat, &sB[buf][rb][0]);
            }
        }
    };

    auto compute = [&](int buf) {
        bf16x8 af[4], bb[4];
#pragma unroll
        for (int mi = 0; mi < 4; ++mi) {
            const int r = wr * 64 + mi * 16 + fr;
            af[mi] = *(const bf16x8*)&sA[buf][r][(fq ^ (r & 3)) * 8];
        }
#pragma unroll
        for (int ni = 0; ni < 4; ++ni) {
            const int r = wc * 64 + ni * 16 + fr;
            const int c0 = (2 * fq) ^ (r & 7);
            const int c1 = (2 * fq + 1) ^ (r & 7);
            const f32x4 lo = *(const f32x4*)&sB[buf][r][c0 * 4];
            const f32x4 hi = *(const f32x4*)&sB[buf][r][c1 * 4];
            bf16x8 t;
            t[0] = (bf16_t)lo[0]; t[1] = (bf16_t)lo[1];
            t[2] = (bf16_t)lo[2]; t[3] = (bf16_t)lo[3];
            t[4] = (bf16_t)hi[0]; t[5] = (bf16_t)hi[1];
            t[6] = (bf16_t)hi[2]; t[7] = (bf16_t)hi[3];
            bb[ni] = t;
        }
#pragma unroll
        for (int mi = 0; mi < 4; ++mi)
#pragma unroll
            for (int ni = 0; ni < 4; ++ni)
                acc[mi][ni] = __builtin_amdgcn_mfma_f32_16x16x32_bf16(
                        af[mi], bb[ni], acc[mi][ni], 0, 0, 0);
    };

    // 2-phase double-buffered pipeline: stage(next) before compute(cur), 1 barrier/K-step
    int cur = 0;
    stage(0, 0);
    __syncthreads();
    for (int kt = 0; kt < KT - 1; ++kt) {
        stage(cur ^ 1, kt + 1);
        compute(cur);
        __syncthreads();
        cur ^= 1;
    }
    compute(cur);

    // epilogue: C/D layout col = lane&15, row = (lane>>4)*4 + reg
#pragma unroll
    for (int mi = 0; mi < 4; ++mi) {
#pragma unroll
        for (int reg = 0; reg < 4; ++reg) {
            const int r = m0 + wr * 64 + mi * 16 + fq * 4 + reg;
            if (r >= mend) continue;
            int tok = 0; float wgt = 0.f;
            if constexpr (EPI == 2) {
                const int slot = slot_of_pos[r];
                tok = slot >> 1;
                wgt = slot_w[slot];
            }
#pragma unroll
            for (int ni = 0; ni < 4; ++ni) {
                const int c = n0 + wc * 64 + ni * 16 + fr;
                if (c >= N) continue;
                float v = acc[mi][ni][reg];
                if constexpr (EPI == 0) {
                    C[(size_t)r * ldc + c] = (bf16_t)v;
                } else if constexpr (EPI == 1) {
                    v += (float)skip[(size_t)r * DIM + c];
                    C[(size_t)r * ldc + c] = (bf16_t)v;
                } else {
                    unsafeAtomicAdd(&outp[(size_t)tok * VOCAB + c], v * wgt);
                }
            }
        }
    }
}

extern "C" void kernel_launch(void* const* d_in, const int* in_sizes, int n_in,
                              void* d_out, int out_size, void* d_ws, size_t ws_size,
                              hipStream_t stream) {
    const float* x        = (const float*)d_in[0];
    const float* w_router = (const float*)d_in[1];
    const float* w_up     = (const float*)d_in[2];
    const float* w_down   = (const float*)d_in[3];
    const float* w_proj   = (const float*)d_in[4];
    float* out = (float*)d_out;
    char* ws = (char*)d_ws;

    int*    counts      = (int*)(ws + 0);
    int*    ntiles      = (int*)(ws + 64);
    int*    tile_e      = (int*)(ws + 128);
    int*    tile_m0     = (int*)(ws + 320);
    int*    tile_mend   = (int*)(ws + 512);
    int*    slot_ids    = (int*)(ws + 1024);
    float*  slot_w      = (float*)(ws + 20480);
    int*    slot_of_pos = (int*)(ws + 36864);
    bf16_t* x_sorted    = (bf16_t*)(ws + 65536);     //  8 MB  [4096][1024]
    bf16_t* h2          = (bf16_t*)(ws + 8454144);   //  8 MB  [4096][1024]
    bf16_t* h1          = (bf16_t*)(ws + 16842752);  // 22 MB  [4096][2752]
    bf16_t* h_raw       = (bf16_t*)(ws + 39387136);  // 45 MB  [4096][5472]

    hipMemsetAsync(d_out, 0, (size_t)out_size * sizeof(float), stream);
    hipMemsetAsync(d_ws, 0, 1024, stream);

    router_kernel<<<NTOK / 4, 256, 0, stream>>>(x, w_router, slot_ids, slot_w, counts);
    sched_kernel<<<1, 512, 0, stream>>>(counts, ntiles, tile_e, tile_m0, tile_mend,
                                        slot_ids, slot_of_pos);
    gather_kernel<<<NSLOT, 256, 0, stream>>>(x, slot_of_pos, x_sorted);

    gemm_kernel<0, true><<<dim3((UPOUT + 127) / 128, MAXTILES), 256, 0, stream>>>(
        x_sorted, DIM, w_up, UPOUT, DIM, 32, (long)NEXP * UPOUT * DIM - 4,
        h_raw, HRAW_LD,
        nullptr, nullptr, nullptr, nullptr, tile_e, tile_m0, tile_mend, ntiles);

    swiglu_kernel<<<dim3(NSLOT, (H1_LD + 255) / 256), 256, 0, stream>>>(h_raw, h1);

    gemm_kernel<1, false><<<dim3(DIM / 128, MAXTILES), 256, 0, stream>>>(
        h1, H1_LD, w_down, DIM, HIDDEN, (HIDDEN + 31) / 32, (long)NEXP * DIM * HIDDEN - 1,
        h2, DIM,
        x_sorted, nullptr, nullptr, nullptr, tile_e, tile_m0, tile_mend, ntiles);

    gemm_kernel<2, true><<<dim3(VOCAB / 128, MAXTILES), 256, 0, stream>>>(
        h2, DIM, w_proj, VOCAB, DIM, 32, (long)NEXP * VOCAB * DIM - 4,
        nullptr, 0,
        nullptr, slot_of_pos, slot_w, out, tile_e, tile_m0, tile_mend, ntiles);
}

// Round 3
// 904.647 us; speedup vs baseline: 2.2747x; 1.2010x over previous
//
#include <hip/hip_runtime.h>
#include <hip/hip_bf16.h>

typedef __bf16 bf16_t;
typedef __bf16 bf16x2 __attribute__((ext_vector_type(2)));
typedef __bf16 bf16x4 __attribute__((ext_vector_type(4)));
typedef __bf16 bf16x8 __attribute__((ext_vector_type(8)));
typedef float f32x4 __attribute__((ext_vector_type(4)));

#define DIM     1024
#define NEXP    8
#define VOCAB   16384
#define HIDDEN  2730
#define UPOUT   5460
#define NTOK    2048
#define NSLOT   4096
#define HRAW_LD 5472
#define H1_LD   2752
#define BM      256
#define MAXTILES 24

__device__ __forceinline__ void gload_lds16(const void* g, void* l) {
    __builtin_amdgcn_global_load_lds((const __attribute__((address_space(1))) void*)g,
                                     (__attribute__((address_space(3))) void*)l, 16, 0, 0);
}
__device__ __forceinline__ void gload_lds4(const void* g, void* l) {
    __builtin_amdgcn_global_load_lds((const __attribute__((address_space(1))) void*)g,
                                     (__attribute__((address_space(3))) void*)l, 4, 0, 0);
}

// ---------------- router: scores, top-2, softmax weights, histogram ----------------
__global__ __launch_bounds__(256) void router_kernel(const float* __restrict__ x,
        const float* __restrict__ wr, int* __restrict__ slot_ids,
        float* __restrict__ slot_w, int* __restrict__ counts) {
    const int lane = threadIdx.x & 63;
    const int wave = threadIdx.x >> 6;
    const int token = blockIdx.x * 4 + wave;
    const float* xrow = x + (size_t)token * DIM;
    float acc[NEXP];
#pragma unroll
    for (int e = 0; e < NEXP; ++e) acc[e] = 0.f;
#pragma unroll
    for (int i = 0; i < DIM / 64; ++i) {
        const int k = i * 64 + lane;
        const float xv = xrow[k];
#pragma unroll
        for (int e = 0; e < NEXP; ++e) acc[e] += xv * wr[e * DIM + k];
    }
#pragma unroll
    for (int off = 32; off > 0; off >>= 1) {
#pragma unroll
        for (int e = 0; e < NEXP; ++e) acc[e] += __shfl_xor(acc[e], off);
    }
    if (lane == 0) {
        float c0 = -1e30f; int b0 = 0;
#pragma unroll
        for (int e = 0; e < NEXP; ++e) if (acc[e] > c0) { c0 = acc[e]; b0 = e; }
        float c1 = -1e30f; int b1 = 0;
#pragma unroll
        for (int e = 0; e < NEXP; ++e) if (e != b0 && acc[e] > c1) { c1 = acc[e]; b1 = e; }
        slot_ids[token * 2 + 0] = b0;
        slot_ids[token * 2 + 1] = b1;
        const float w0 = 1.f / (1.f + expf(c1 - c0));
        slot_w[token * 2 + 0] = w0;
        slot_w[token * 2 + 1] = 1.f - w0;
        atomicAdd(&counts[b0], 1);
        atomicAdd(&counts[b1], 1);
    }
}

// ---------------- scheduler: offsets, tile list (BM rows), stable counting-sort ranks ---
__global__ __launch_bounds__(512) void sched_kernel(const int* __restrict__ counts,
        int* __restrict__ ntiles, int* __restrict__ tile_e, int* __restrict__ tile_m0,
        int* __restrict__ tile_mend, const int* __restrict__ slot_ids,
        int* __restrict__ slot_of_pos) {
    __shared__ int offs[NEXP];
    if (threadIdx.x == 0) {
        int o = 0, nt = 0;
        for (int e = 0; e < NEXP; ++e) {
            offs[e] = o;
            const int c = counts[e];
            for (int m = 0; m < c; m += BM) {
                tile_e[nt] = e; tile_m0[nt] = o + m; tile_mend[nt] = o + c; ++nt;
            }
            o += c;
        }
        *ntiles = nt;
    }
    __syncthreads();
    const int e = threadIdx.x >> 6;
    const int lane = threadIdx.x & 63;
    int base = offs[e];
    for (int ch = 0; ch < NSLOT / 64; ++ch) {
        const int i = ch * 64 + lane;
        const int id = slot_ids[i];
        const unsigned long long m = __ballot(id == e);
        if (id == e) {
            const int rank = __popcll(m & ((1ull << lane) - 1ull));
            slot_of_pos[base + rank] = i;
        }
        base += __popcll(m);
    }
}

// ---------------- gather tokens into sorted order, fp32 -> bf16 ----------------
__global__ __launch_bounds__(256) void gather_kernel(const float* __restrict__ x,
        const int* __restrict__ slot_of_pos, bf16_t* __restrict__ xs) {
    const int row = blockIdx.x;
    const int t = threadIdx.x;
    const int tok = slot_of_pos[row] >> 1;
    const float4 v = *(const float4*)(x + (size_t)tok * DIM + t * 4);
    bf16x4 o;
    o.x = (bf16_t)v.x; o.y = (bf16_t)v.y; o.z = (bf16_t)v.z; o.w = (bf16_t)v.w;
    *(bf16x4*)(xs + (size_t)row * DIM + t * 4) = o;
}

// ---------------- swiglu: h1 = lin * silu(gate), zero-pad K tail ----------------
__global__ __launch_bounds__(256) void swiglu_kernel(const bf16_t* __restrict__ hraw,
        bf16_t* __restrict__ h1) {
    const int row = blockIdx.x;
    const int col = blockIdx.y * 256 + threadIdx.x;
    if (col >= H1_LD) return;
    float o = 0.f;
    if (col < HIDDEN) {
        const float a = (float)hraw[(size_t)row * HRAW_LD + col];
        const float g = (float)hraw[(size_t)row * HRAW_LD + col + HIDDEN];
        o = a * (g / (1.f + expf(-g)));
    }
    h1[(size_t)row * H1_LD + col] = (bf16_t)o;
}

// ---------------- grouped GEMM: C[m,n] = sum_k A[m,k] * W[n,k]
// BM=256 x BN=128, BK=32, 512 threads (8 waves, 4Mx2N), 64 KB LDS double-buffer.
// Counted-vmcnt pipeline: stage(t+1); vmcnt(NLOADS); barrier; compute(t); barrier.
// A bf16 via global_load_lds(16B); W fp32 via global_load_lds(16B or 4B), cvt after ds_read.
// LDS XOR-swizzled via pre-swizzled global source (linear dest, rule 21).
template <int EPI, bool BW16, int NLOADS>
__global__ __launch_bounds__(512, 4) void gemm_kernel(
        const bf16_t* __restrict__ A, int lda,
        const float* __restrict__ B, int N, int K, int KT, long bLast,
        bf16_t* __restrict__ C, int ldc,
        const bf16_t* __restrict__ skip,
        const int* __restrict__ slot_of_pos,
        const float* __restrict__ slot_w,
        float* __restrict__ outp,
        const int* __restrict__ tile_e,
        const int* __restrict__ tile_m0,
        const int* __restrict__ tile_mend,
        const int* __restrict__ ntiles) {
    if (blockIdx.y >= (unsigned)*ntiles) return;
    const int e = tile_e[blockIdx.y];
    const int m0 = tile_m0[blockIdx.y];
    const int mend = tile_mend[blockIdx.y];
    const int n0 = blockIdx.x * 128;
    const float* __restrict__ Bexp = B + (size_t)e * N * K;

    __shared__ bf16_t sA[2][BM][32];    // 16 KB x2, 64B rows, unit16 ^= (row&3)
    __shared__ float  sB[2][128][32];   // 16 KB x2, 128B rows, unit16 ^= (row&7)

    const int tid = threadIdx.x;
    const int lane = tid & 63;
    const int wave = tid >> 6;
    const int wr = wave >> 1;   // 0..3 -> M offset wr*64
    const int wc = wave & 1;    // 0..1 -> N offset wc*64
    const int fr = lane & 15;
    const int fq = lane >> 4;

    f32x4 acc[4][4] = {};

    auto stage = [&](int buf, int kt) {
        const int k0 = kt * 32;
        // A tile: 16 KB = 16 x 1KB wave-issues (2/wave). lane -> row rb+(l>>2), unit l&3
#pragma unroll
        for (int j = 0; j < 2; ++j) {
            const int rb = (wave * 2 + j) * 16;
            const int r = rb + (lane >> 2);
            const int gr = min(m0 + r, NSLOT - 1);
            const int c16 = (lane & 3) ^ (r & 3);          // pre-swizzled source unit
            gload_lds16(A + (size_t)gr * lda + k0 + c16 * 8, &sA[buf][rb][0]);
        }
        if constexpr (BW16) {
            // B tile: 16 KB = 16 x 1KB wave-issues (2/wave). row rb+(l>>3), unit l&7
#pragma unroll
            for (int j = 0; j < 2; ++j) {
                const int rb = (wave * 2 + j) * 8;
                const int r = rb + (lane >> 3);
                const int gr = min(n0 + r, N - 1);
                const int c16 = (lane & 7) ^ (r & 7);
                gload_lds16(Bexp + (size_t)gr * K + k0 + c16 * 4, &sB[buf][rb][0]);
            }
        } else {
            // rows only 8B-aligned (K=2730): 4B lanes, 64 x 256B issues (8/wave)
#pragma unroll
            for (int j = 0; j < 8; ++j) {
                const int rb = (wave * 8 + j) * 2;
                const int r = rb + (lane >> 5);
                const int gr = min(n0 + r, N - 1);
                const int c16 = ((lane >> 2) & 7) ^ (r & 7);
                long flat = (long)e * N * K + (long)gr * K + k0 + c16 * 4 + (lane & 3);
                if (flat > bLast) flat = bLast;   // K-tail: A is zero there, value irrelevant
                gload_lds4(B + flat, &sB[buf][rb][0]);
            }
        }
    };

    auto compute = [&](int buf) {
        bf16x8 af[4];
#pragma unroll
        for (int mi = 0; mi < 4; ++mi) {
            const int r = wr * 64 + mi * 16 + fr;
            af[mi] = *(const bf16x8*)&sA[buf][r][(fq ^ (r & 3)) * 8];
        }
        __builtin_amdgcn_s_setprio(1);
#pragma unroll
        for (int ni = 0; ni < 4; ++ni) {
            const int r = wc * 64 + ni * 16 + fr;
            const f32x4 lo = *(const f32x4*)&sB[buf][r][((2 * fq) ^ (r & 7)) * 4];
            const f32x4 hi = *(const f32x4*)&sB[buf][r][((2 * fq + 1) ^ (r & 7)) * 4];
            bf16x8 t;
            t[0] = (bf16_t)lo[0]; t[1] = (bf16_t)lo[1];
            t[2] = (bf16_t)lo[2]; t[3] = (bf16_t)lo[3];
            t[4] = (bf16_t)hi[0]; t[5] = (bf16_t)hi[1];
            t[6] = (bf16_t)hi[2]; t[7] = (bf16_t)hi[3];
#pragma unroll
            for (int mi = 0; mi < 4; ++mi)
                acc[mi][ni] = __builtin_amdgcn_mfma_f32_16x16x32_bf16(
                        af[mi], t, acc[mi][ni], 0, 0, 0);
        }
        __builtin_amdgcn_s_setprio(0);
    };

    // counted-vmcnt double-buffered pipeline (T3/T4): prefetch stays in flight
    stage(0, 0);
    int cur = 0;
    for (int kt = 0; kt < KT - 1; ++kt) {
        stage(cur ^ 1, kt + 1);
        asm volatile("s_waitcnt vmcnt(%0)" :: "n"(NLOADS) : "memory");
        __builtin_amdgcn_s_barrier();           // tile kt fully in LDS for all waves
        asm volatile("" ::: "memory");
        compute(cur);
        asm volatile("" ::: "memory");
        __builtin_amdgcn_s_barrier();           // all waves done reading buf[cur]
        cur ^= 1;
    }
    asm volatile("s_waitcnt vmcnt(0)" ::: "memory");
    __builtin_amdgcn_s_barrier();
    asm volatile("" ::: "memory");
    compute(cur);

    // epilogue: C/D layout col = lane&15, row = (lane>>4)*4 + reg
#pragma unroll
    for (int mi = 0; mi < 4; ++mi) {
#pragma unroll
        for (int reg = 0; reg < 4; ++reg) {
            const int r = m0 + wr * 64 + mi * 16 + fq * 4 + reg;
            if (r >= mend) continue;
            int tok = 0; float wgt = 0.f;
            if constexpr (EPI == 2) {
                const int slot = slot_of_pos[r];
                tok = slot >> 1;
                wgt = slot_w[slot];
            }
#pragma unroll
            for (int ni = 0; ni < 4; ++ni) {
                const int c = n0 + wc * 64 + ni * 16 + fr;
                if (c >= N) continue;
                float v = acc[mi][ni][reg];
                if constexpr (EPI == 0) {
                    C[(size_t)r * ldc + c] = (bf16_t)v;
                } else if constexpr (EPI == 1) {
                    v += (float)skip[(size_t)r * DIM + c];
                    C[(size_t)r * ldc + c] = (bf16_t)v;
                } else {
                    unsafeAtomicAdd(&outp[(size_t)tok * VOCAB + c], v * wgt);
                }
            }
        }
    }
}

extern "C" void kernel_launch(void* const* d_in, const int* in_sizes, int n_in,
                              void* d_out, int out_size, void* d_ws, size_t ws_size,
                              hipStream_t stream) {
    const float* x        = (const float*)d_in[0];
    const float* w_router = (const float*)d_in[1];
    const float* w_up     = (const float*)d_in[2];
    const float* w_down   = (const float*)d_in[3];
    const float* w_proj   = (const float*)d_in[4];
    float* out = (float*)d_out;
    char* ws = (char*)d_ws;

    int*    counts      = (int*)(ws + 0);
    int*    ntiles      = (int*)(ws + 64);
    int*    tile_e      = (int*)(ws + 128);
    int*    tile_m0     = (int*)(ws + 320);
    int*    tile_mend   = (int*)(ws + 512);
    int*    slot_ids    = (int*)(ws + 1024);
    float*  slot_w      = (float*)(ws + 20480);
    int*    slot_of_pos = (int*)(ws + 36864);
    bf16_t* x_sorted    = (bf16_t*)(ws + 65536);     //  8 MB  [4096][1024]
    bf16_t* h2          = (bf16_t*)(ws + 8454144);   //  8 MB  [4096][1024]
    bf16_t* h1          = (bf16_t*)(ws + 16842752);  // 22 MB  [4096][2752]
    bf16_t* h_raw       = (bf16_t*)(ws + 39387136);  // 45 MB  [4096][5472]

    hipMemsetAsync(d_out, 0, (size_t)out_size * sizeof(float), stream);
    hipMemsetAsync(d_ws, 0, 1024, stream);

    router_kernel<<<NTOK / 4, 256, 0, stream>>>(x, w_router, slot_ids, slot_w, counts);
    sched_kernel<<<1, 512, 0, stream>>>(counts, ntiles, tile_e, tile_m0, tile_mend,
                                        slot_ids, slot_of_pos);
    gather_kernel<<<NSLOT, 256, 0, stream>>>(x, slot_of_pos, x_sorted);

    gemm_kernel<0, true, 4><<<dim3((UPOUT + 127) / 128, MAXTILES), 512, 0, stream>>>(
        x_sorted, DIM, w_up, UPOUT, DIM, 32, (long)NEXP * UPOUT * DIM - 4,
        h_raw, HRAW_LD,
        nullptr, nullptr, nullptr, nullptr, tile_e, tile_m0, tile_mend, ntiles);

    swiglu_kernel<<<dim3(NSLOT, (H1_LD + 255) / 256), 256, 0, stream>>>(h_raw, h1);

    gemm_kernel<1, false, 10><<<dim3(DIM / 128, MAXTILES), 512, 0, stream>>>(
        h1, H1_LD, w_down, DIM, HIDDEN, (HIDDEN + 31) / 32, (long)NEXP * DIM * HIDDEN - 1,
        h2, DIM,
        x_sorted, nullptr, nullptr, nullptr, tile_e, tile_m0, tile_mend, ntiles);

    gemm_kernel<2, true, 4><<<dim3(VOCAB / 128, MAXTILES), 512, 0, stream>>>(
        h2, DIM, w_proj, VOCAB, DIM, 32, (long)NEXP * VOCAB * DIM - 4,
        nullptr, 0,
        nullptr, slot_of_pos, slot_w, out, tile_e, tile_m0, tile_mend, ntiles);
}